// Round 1
// baseline (420.988 us; speedup 1.0000x reference)
//
#include <hip/hip_runtime.h>
#include <cstdint>
#include <cstddef>

#define NUM_HEADS 16
#define HEAD_DIM  64
#define DMODEL    1024
#define BATCH     4
#define SEQ       2048
#define MROWS     (BATCH*SEQ)   // 8192
#define N_QKV     (3*DMODEL)    // 3072

typedef __attribute__((ext_vector_type(8))) short bf16x8;
typedef __attribute__((ext_vector_type(4))) float f32x4;

__device__ __forceinline__ short f2bf(float f){
  union { float f; uint32_t u; } w; w.f = f;
  uint32_t r = w.u + 0x7fffu + ((w.u >> 16) & 1u);
  return (short)(r >> 16);
}

typedef __attribute__((address_space(3))) short       lds_short_t;
typedef __attribute__((address_space(1))) const short glb_short_t;

// dest = wave-uniform LDS base; HW writes base + lane*16 (16B per lane)
__device__ __forceinline__ void gload_lds16(const short* g, short* lds){
  __builtin_amdgcn_global_load_lds((glb_short_t*)g, (lds_short_t*)lds, 16, 0, 0);
}

// ---------------- f32 -> bf16, same layout (4 elems/thread) ----------------
__global__ void k_cvt(const float* __restrict__ in, short* __restrict__ out, int n4){
  int i = blockIdx.x*256 + threadIdx.x;
  if (i >= n4) return;
  float4 v = reinterpret_cast<const float4*>(in)[i];
  short4 o; o.x = f2bf(v.x); o.y = f2bf(v.y); o.z = f2bf(v.z); o.w = f2bf(v.w);
  reinterpret_cast<short4*>(out)[i] = o;
}

// ---------------- f32 [R][C] -> bf16 [C][R] (64x64 LDS tile) ----------------
__global__ void k_cvt_t(const float* __restrict__ in, short* __restrict__ out, int R, int C){
  __shared__ short t[64][65];
  int cb = blockIdx.x*64, rb = blockIdx.y*64;
  int tx = threadIdx.x & 63, ty = threadIdx.x >> 6;
  #pragma unroll
  for (int i = ty; i < 64; i += 4)
    t[i][tx] = f2bf(in[(size_t)(rb+i)*C + cb + tx]);
  __syncthreads();
  #pragma unroll
  for (int i = ty; i < 64; i += 4)
    out[(size_t)(cb+i)*R + rb + tx] = t[tx][i];
}

// ---------------- 128x128 bf16 GEMM, BK=32, 4 waves ----------------
// A [M][K] bf16 row-major ; Bt [N][K] bf16 (B transposed) ; both K-contig.
// MODE 0: epilogue scatters qkv -> Qb/Kb [bh][s][64], Vt [bh][64][s]  (bf16)
// MODE 1: epilogue writes fp32 Out[M][N] + bias
template<int MODE>
__global__ __launch_bounds__(256, 2) void k_gemm(
    const short* __restrict__ A, const short* __restrict__ Bt,
    const float* __restrict__ bias,
    short* __restrict__ Qb, short* __restrict__ Kb, short* __restrict__ Vt,
    float* __restrict__ Out, int K)
{
  __shared__ short As[128*32];
  __shared__ short Bs[128*32];
  const int lane = threadIdx.x & 63, wave = threadIdx.x >> 6;
  const int wr = wave >> 1, wc = wave & 1;
  const int m0 = blockIdx.y * 128, n0 = blockIdx.x * 128;

  f32x4 acc[4][4] = {};

  // staging geometry: chunk = 16 rows x (4 segs of 16B); swizzle seg ^= row&3 on SOURCE
  const int srow = lane >> 2;
  const int sseg = (lane & 3) ^ (srow & 3);
  const int nkt = K >> 5;
  for (int kt = 0; kt < nkt; ++kt){
    __syncthreads();
    #pragma unroll
    for (int c = 0; c < 2; ++c){
      const int ch = wave*2 + c;
      const int r  = ch*16 + srow;
      gload_lds16(A  + (size_t)(m0 + r)*K + kt*32 + sseg*8, As + ch*512);
      gload_lds16(Bt + (size_t)(n0 + r)*K + kt*32 + sseg*8, Bs + ch*512);
    }
    __syncthreads();
    bf16x8 af[4], bfr[4];
    #pragma unroll
    for (int m = 0; m < 4; ++m){
      const int ra = wr*64 + m*16 + (lane & 15);
      af[m]  = *reinterpret_cast<const bf16x8*>(As + ra*32 + (((lane>>4) ^ (ra & 3))*8));
      const int rb = wc*64 + m*16 + (lane & 15);
      bfr[m] = *reinterpret_cast<const bf16x8*>(Bs + rb*32 + (((lane>>4) ^ (rb & 3))*8));
    }
    #pragma unroll
    for (int m = 0; m < 4; ++m)
      #pragma unroll
      for (int n = 0; n < 4; ++n)
        acc[m][n] = __builtin_amdgcn_mfma_f32_16x16x32_bf16(af[m], bfr[n], acc[m][n], 0, 0, 0);
  }

  // epilogue: C frag mapping col=lane&15, row=(lane>>4)*4+i  [m89/m91]
  #pragma unroll
  for (int m = 0; m < 4; ++m){
    const int row = m0 + wr*64 + m*16 + ((lane>>4)<<2);
    #pragma unroll
    for (int n = 0; n < 4; ++n){
      const int col = n0 + wc*64 + n*16 + (lane & 15);
      const float bv = bias[col];
      #pragma unroll
      for (int i = 0; i < 4; ++i){
        const int r = row + i;
        const float v = acc[m][n][i] + bv;
        if (MODE == 0){
          const int h = col / 192, q = col % 192;
          const int b = r >> 11, s = r & 2047;
          const int bh = b*NUM_HEADS + h;
          const short o = f2bf(v);
          if (q < 64)       Qb[((size_t)bh*SEQ + s)*64 + q]          = o;
          else if (q < 128) Kb[((size_t)bh*SEQ + s)*64 + (q-64)]     = o;
          else              Vt[((size_t)bh*64 + (q-128))*SEQ + s]    = o;
        } else {
          Out[(size_t)r*DMODEL + col] = v;
        }
      }
    }
  }
}

// ---------------- flash attention: 128 q-rows/block, 4 waves x 32 q-rows ----------------
// Qb,Kb [bh][S][64] bf16 ; Vt [bh][64][S] bf16 ; Ob [b][s][h*64+d] bf16
__global__ __launch_bounds__(256, 2) void k_attn(
    const short* __restrict__ Qb, const short* __restrict__ Kb,
    const short* __restrict__ Vt, short* __restrict__ Ob)
{
  __shared__ short Ks[128*64];      // [key][d], 16B-chunk swizzle ^ (key&7)
  __shared__ short Vs[64*128];      // [d][key], 16B-chunk swizzle ^ (d&7)
  __shared__ short Ps[4][32*136];   // per-wave P [32][136] (pad breaks bank aliasing)
  const int lane = threadIdx.x & 63, wave = threadIdx.x >> 6;
  const int bh = blockIdx.y;
  const int q0 = blockIdx.x*128 + wave*32;
  const float cs = 0.125f * 1.4426950408889634f;  // 1/sqrt(64) * log2(e)

  bf16x8 qf[2][2];
  #pragma unroll
  for (int m = 0; m < 2; ++m)
    #pragma unroll
    for (int kb = 0; kb < 2; ++kb){
      const int s = q0 + m*16 + (lane & 15);
      const int d = kb*32 + ((lane>>4)<<3);
      qf[m][kb] = *reinterpret_cast<const bf16x8*>(Qb + ((size_t)bh*SEQ + s)*64 + d);
    }

  f32x4 acc[2][4] = {};
  float mrun[2][4], lrun[2][4];
  #pragma unroll
  for (int m = 0; m < 2; ++m)
    #pragma unroll
    for (int i = 0; i < 4; ++i){ mrun[m][i] = -1e30f; lrun[m][i] = 0.f; }

  short* Pw = &Ps[wave][0];

  for (int kt = 0; kt < SEQ/128; ++kt){
    __syncthreads();
    { // stage K tile [128][64]: chunks of 8 rows x 8 segs
      const int r8 = lane >> 3, sg = lane & 7;
      #pragma unroll
      for (int c = 0; c < 4; ++c){
        const int ch = wave*4 + c;
        const int r  = ch*8 + r8;
        const int seg = sg ^ (r & 7);
        gload_lds16(Kb + ((size_t)bh*SEQ + kt*128 + r)*64 + seg*8, Ks + ch*512);
      }
      // stage V tile [64][128]: chunks of 4 d-rows x 16 segs
      const int d4 = lane >> 4, sg2 = lane & 15;
      #pragma unroll
      for (int c = 0; c < 4; ++c){
        const int ch = wave*4 + c;
        const int d  = ch*4 + d4;
        const int seg = sg2 ^ (d & 7);
        gload_lds16(Vt + ((size_t)bh*64 + d)*SEQ + kt*128 + seg*8, Vs + ch*512);
      }
    }
    __syncthreads();

    // QK^T : 32 q-rows x 128 keys
    f32x4 sc[2][8] = {};
    #pragma unroll
    for (int n = 0; n < 8; ++n){
      const int key = n*16 + (lane & 15);
      #pragma unroll
      for (int kb = 0; kb < 2; ++kb){
        const int seg = (kb*4 + (lane>>4)) ^ (key & 7);
        const bf16x8 kf = *reinterpret_cast<const bf16x8*>(Ks + key*64 + seg*8);
        #pragma unroll
        for (int m = 0; m < 2; ++m)
          sc[m][n] = __builtin_amdgcn_mfma_f32_16x16x32_bf16(qf[m][kb], kf, sc[m][n], 0, 0, 0);
      }
    }

    // online softmax (exp2 domain); rows live per (m,i) with g=lane>>4
    #pragma unroll
    for (int m = 0; m < 2; ++m){
      #pragma unroll
      for (int i = 0; i < 4; ++i){
        float v = sc[m][0][i];
        #pragma unroll
        for (int n = 1; n < 8; ++n) v = fmaxf(v, sc[m][n][i]);
        v = fmaxf(v, __shfl_xor(v, 1));
        v = fmaxf(v, __shfl_xor(v, 2));
        v = fmaxf(v, __shfl_xor(v, 4));
        v = fmaxf(v, __shfl_xor(v, 8));
        const float mnew = fmaxf(mrun[m][i], v);
        const float corr = exp2f((mrun[m][i] - mnew)*cs);
        mrun[m][i] = mnew;
        lrun[m][i] *= corr;
        #pragma unroll
        for (int dn = 0; dn < 4; ++dn) acc[m][dn][i] *= corr;
        float ps = 0.f;
        const int prow = m*16 + ((lane>>4)<<2) + i;
        #pragma unroll
        for (int n = 0; n < 8; ++n){
          const float p = exp2f((sc[m][n][i] - mnew)*cs);
          ps += p;
          Pw[prow*136 + n*16 + (lane & 15)] = f2bf(p);
        }
        ps += __shfl_xor(ps, 1);
        ps += __shfl_xor(ps, 2);
        ps += __shfl_xor(ps, 4);
        ps += __shfl_xor(ps, 8);
        lrun[m][i] += ps;
      }
    }

    // PV : P[32][128] @ V[128][64]
    #pragma unroll
    for (int kb = 0; kb < 4; ++kb){
      bf16x8 pf[2];
      #pragma unroll
      for (int m = 0; m < 2; ++m)
        pf[m] = *reinterpret_cast<const bf16x8*>(Pw + (m*16 + (lane & 15))*136 + kb*32 + ((lane>>4)<<3));
      #pragma unroll
      for (int dn = 0; dn < 4; ++dn){
        const int dcol = dn*16 + (lane & 15);
        const int seg = (kb*4 + (lane>>4)) ^ (dcol & 7);
        const bf16x8 vf = *reinterpret_cast<const bf16x8*>(Vs + dcol*128 + seg*8);
        #pragma unroll
        for (int m = 0; m < 2; ++m)
          acc[m][dn] = __builtin_amdgcn_mfma_f32_16x16x32_bf16(pf[m], vf, acc[m][dn], 0, 0, 0);
      }
    }
  }

  // epilogue: normalize and write [b][s][h*64+d]
  const int b = bh >> 4, h = bh & 15;
  #pragma unroll
  for (int m = 0; m < 2; ++m)
    #pragma unroll
    for (int i = 0; i < 4; ++i){
      const int s = q0 + m*16 + ((lane>>4)<<2) + i;
      const float inv = 1.f / lrun[m][i];
      #pragma unroll
      for (int dn = 0; dn < 4; ++dn){
        const int d = dn*16 + (lane & 15);
        Ob[((size_t)b*SEQ + s)*DMODEL + h*64 + d] = f2bf(acc[m][dn][i] * inv);
      }
    }
}

extern "C" void kernel_launch(void* const* d_in, const int* in_sizes, int n_in,
                              void* d_out, int out_size, void* d_ws, size_t ws_size,
                              hipStream_t stream)
{
  const float* x    = (const float*)d_in[0];
  const float* Wqkv = (const float*)d_in[1];
  const float* bqkv = (const float*)d_in[2];
  const float* Wout = (const float*)d_in[3];
  const float* bout = (const float*)d_in[4];
  float* out = (float*)d_out;

  short* ws  = (short*)d_ws;
  short* xb  = ws;                                  // [8192][1024] bf16; reused as attn output
  short* wqt = xb  + (size_t)MROWS*DMODEL;          // [3072][1024]
  short* wot = wqt + (size_t)N_QKV*DMODEL;          // [1024][1024]
  short* Qb  = wot + (size_t)DMODEL*DMODEL;         // [64][2048][64]
  short* Kb  = Qb  + (size_t)MROWS*DMODEL;
  short* Vt  = Kb  + (size_t)MROWS*DMODEL;          // [64][64][2048]

  k_cvt<<<dim3(MROWS*DMODEL/4/256), dim3(256), 0, stream>>>(x, xb, MROWS*DMODEL/4);
  k_cvt_t<<<dim3(N_QKV/64, DMODEL/64), dim3(256), 0, stream>>>(Wqkv, wqt, DMODEL, N_QKV);
  k_cvt_t<<<dim3(DMODEL/64, DMODEL/64), dim3(256), 0, stream>>>(Wout, wot, DMODEL, DMODEL);

  k_gemm<0><<<dim3(N_QKV/128, MROWS/128), dim3(256), 0, stream>>>(
      xb, wqt, bqkv, Qb, Kb, Vt, nullptr, DMODEL);

  k_attn<<<dim3(SEQ/128, BATCH*NUM_HEADS), dim3(256), 0, stream>>>(Qb, Kb, Vt, xb);

  k_gemm<1><<<dim3(DMODEL/128, MROWS/128), dim3(256), 0, stream>>>(
      xb, wot, bout, nullptr, nullptr, nullptr, out, DMODEL);
}

// Round 2
// 338.905 us; speedup vs baseline: 1.2422x; 1.2422x over previous
//
#include <hip/hip_runtime.h>
#include <cstdint>
#include <cstddef>

#define NUM_HEADS 16
#define HEAD_DIM  64
#define DMODEL    1024
#define BATCH     4
#define SEQ       2048
#define MROWS     (BATCH*SEQ)   // 8192
#define N_QKV     (3*DMODEL)    // 3072

typedef __attribute__((ext_vector_type(8))) short bf16x8;
typedef __attribute__((ext_vector_type(4))) float f32x4;
typedef __attribute__((ext_vector_type(16))) float f32x16;
typedef __attribute__((ext_vector_type(4))) uint32_t u32x4;

__device__ __forceinline__ short f2bf(float f){
  union { float f; uint32_t u; } w; w.f = f;
  uint32_t r = w.u + 0x7fffu + ((w.u >> 16) & 1u);
  return (short)(r >> 16);
}

typedef __attribute__((address_space(3))) short       lds_short_t;
typedef __attribute__((address_space(1))) const short glb_short_t;

// dest = wave-uniform LDS base; HW writes base + lane*16 (16B per lane)
__device__ __forceinline__ void gload_lds16(const short* g, short* lds){
  __builtin_amdgcn_global_load_lds((glb_short_t*)g, (lds_short_t*)lds, 16, 0, 0);
}

// exchange: a' = {a.lo, b.lo(partner)}, b' = {a.hi(partner), b.hi}
__device__ __forceinline__ void plane32_swap(uint32_t &a, uint32_t &b){
#if __has_builtin(__builtin_amdgcn_permlane32_swap)
  auto r = __builtin_amdgcn_permlane32_swap(a, b, false, false);
  a = r[0]; b = r[1];
#else
  asm volatile("v_permlane32_swap_b32 %0, %1" : "+v"(a), "+v"(b));
#endif
}

// ---------------- f32 -> bf16, same layout (4 elems/thread) ----------------
__global__ void k_cvt(const float* __restrict__ in, short* __restrict__ out, int n4){
  int i = blockIdx.x*256 + threadIdx.x;
  if (i >= n4) return;
  float4 v = reinterpret_cast<const float4*>(in)[i];
  short4 o; o.x = f2bf(v.x); o.y = f2bf(v.y); o.z = f2bf(v.z); o.w = f2bf(v.w);
  reinterpret_cast<short4*>(out)[i] = o;
}

// ---------------- f32 [R][C] -> bf16 [C][R] (64x64 LDS tile) ----------------
__global__ void k_cvt_t(const float* __restrict__ in, short* __restrict__ out, int R, int C){
  __shared__ short t[64][65];
  int cb = blockIdx.x*64, rb = blockIdx.y*64;
  int tx = threadIdx.x & 63, ty = threadIdx.x >> 6;
  #pragma unroll
  for (int i = ty; i < 64; i += 4)
    t[i][tx] = f2bf(in[(size_t)(rb+i)*C + cb + tx]);
  __syncthreads();
  #pragma unroll
  for (int i = ty; i < 64; i += 4)
    out[(size_t)(cb+i)*R + rb + tx] = t[tx][i];
}

// ---------------- 128x128 bf16 GEMM, BK=32, 4 waves ----------------
template<int MODE>
__global__ __launch_bounds__(256, 2) void k_gemm(
    const short* __restrict__ A, const short* __restrict__ Bt,
    const float* __restrict__ bias,
    short* __restrict__ Qb, short* __restrict__ Kb, short* __restrict__ Vt,
    float* __restrict__ Out, int K)
{
  __shared__ short As[128*32];
  __shared__ short Bs[128*32];
  const int lane = threadIdx.x & 63, wave = threadIdx.x >> 6;
  const int wr = wave >> 1, wc = wave & 1;
  const int m0 = blockIdx.y * 128, n0 = blockIdx.x * 128;

  f32x4 acc[4][4] = {};

  const int srow = lane >> 2;
  const int sseg = (lane & 3) ^ (srow & 3);
  const int nkt = K >> 5;
  for (int kt = 0; kt < nkt; ++kt){
    __syncthreads();
    #pragma unroll
    for (int c = 0; c < 2; ++c){
      const int ch = wave*2 + c;
      const int r  = ch*16 + srow;
      gload_lds16(A  + (size_t)(m0 + r)*K + kt*32 + sseg*8, As + ch*512);
      gload_lds16(Bt + (size_t)(n0 + r)*K + kt*32 + sseg*8, Bs + ch*512);
    }
    __syncthreads();
    bf16x8 af[4], bfr[4];
    #pragma unroll
    for (int m = 0; m < 4; ++m){
      const int ra = wr*64 + m*16 + (lane & 15);
      af[m]  = *reinterpret_cast<const bf16x8*>(As + ra*32 + (((lane>>4) ^ (ra & 3))*8));
      const int rb = wc*64 + m*16 + (lane & 15);
      bfr[m] = *reinterpret_cast<const bf16x8*>(Bs + rb*32 + (((lane>>4) ^ (rb & 3))*8));
    }
    #pragma unroll
    for (int m = 0; m < 4; ++m)
      #pragma unroll
      for (int n = 0; n < 4; ++n)
        acc[m][n] = __builtin_amdgcn_mfma_f32_16x16x32_bf16(af[m], bfr[n], acc[m][n], 0, 0, 0);
  }

  #pragma unroll
  for (int m = 0; m < 4; ++m){
    const int row = m0 + wr*64 + m*16 + ((lane>>4)<<2);
    #pragma unroll
    for (int n = 0; n < 4; ++n){
      const int col = n0 + wc*64 + n*16 + (lane & 15);
      const float bv = bias[col];
      #pragma unroll
      for (int i = 0; i < 4; ++i){
        const int r = row + i;
        const float v = acc[m][n][i] + bv;
        if (MODE == 0){
          const int h = col / 192, q = col % 192;
          const int b = r >> 11, s = r & 2047;
          const int bh = b*NUM_HEADS + h;
          const short o = f2bf(v);
          if (q < 64)       Qb[((size_t)bh*SEQ + s)*64 + q]          = o;
          else if (q < 128) Kb[((size_t)bh*SEQ + s)*64 + (q-64)]     = o;
          else              Vt[((size_t)bh*64 + (q-128))*SEQ + s]    = o;
        } else {
          Out[(size_t)r*DMODEL + col] = v;
        }
      }
    }
  }
}

// ---------------- flash attention v2: swapped QK^T, in-register softmax ----
// 4 waves x 32 q-rows = 128 q/block. KVBLK=64, K/V double-buffered in LDS.
// Qb,Kb [bh][S][64] bf16 ; Vt [bh][64][S] bf16 ; Ob [b][s][h*64+d] bf16
__global__ __launch_bounds__(256, 3) void k_attn(
    const short* __restrict__ Qb, const short* __restrict__ Kb,
    const short* __restrict__ Vt, short* __restrict__ Ob)
{
  __shared__ short Ks[2][64*64];   // [key][d], 16B-seg swizzle ^ (key&7)
  __shared__ short Vs[2][64*64];   // [d][key], 16B-seg swizzle ^ (d&7)
  const int lane = threadIdx.x & 63, wave = threadIdx.x >> 6;
  const int l31 = lane & 31, hi = lane >> 5;
  const int bh = blockIdx.y;
  const int q0 = blockIdx.x*128 + wave*32;
  const float cs = 0.125f * 1.4426950408889634f;  // 1/sqrt(64) * log2(e)

  // Q fragments: lane owns q-row q0+l31; qf[ks] covers d = 16ks + 8hi .. +8
  bf16x8 qf[4];
  {
    const short* qrow = Qb + ((size_t)bh*SEQ + q0 + l31)*64;
    #pragma unroll
    for (int ks = 0; ks < 4; ++ks)
      qf[ks] = *reinterpret_cast<const bf16x8*>(qrow + ks*16 + hi*8);
  }

  f32x16 oacc[2] = {};          // O in C-layout: row q=(r&3)+8*(r>>2)+4hi, col d=dt*32+l31
  float mrun = -1e30f, lrun = 0.f;

  const int r8 = lane >> 3, sg = lane & 7;

  auto stage = [&](int bsel, int kt){
    #pragma unroll
    for (int c = 0; c < 2; ++c){
      const int ch  = wave*2 + c;
      const int row = ch*8 + r8;
      const int seg = sg ^ (row & 7);
      gload_lds16(Kb + ((size_t)bh*SEQ + kt*64 + row)*64 + seg*8, &Ks[bsel][ch*512]);
      gload_lds16(Vt + ((size_t)bh*64 + row)*SEQ + kt*64 + seg*8, &Vs[bsel][ch*512]);
    }
  };

  stage(0, 0);
  __syncthreads();

  for (int kt = 0; kt < SEQ/64; ++kt){
    const int cur = kt & 1;
    if (kt < SEQ/64 - 1) stage(cur ^ 1, kt + 1);

    // ---- swapped QK^T: p[t] = K_tile(t) x Q^T ; lane holds 16 keys of its q-row
    f32x16 p[2] = {};
    #pragma unroll
    for (int t = 0; t < 2; ++t){
      const int key = t*32 + l31;
      const short* krow = &Ks[cur][key*64];
      const int sw = key & 7;
      #pragma unroll
      for (int ks = 0; ks < 4; ++ks){
        const bf16x8 kf = *reinterpret_cast<const bf16x8*>(krow + (((2*ks + hi) ^ sw) * 8));
        p[t] = __builtin_amdgcn_mfma_f32_32x32x16_bf16(kf, qf[ks], p[t], 0, 0, 0);
      }
    }

    // ---- online softmax: row max/sum in-lane + 1 partner swap
    float pmax = p[0][0];
    #pragma unroll
    for (int r = 1; r < 16; ++r) pmax = fmaxf(pmax, p[0][r]);
    #pragma unroll
    for (int r = 0; r < 16; ++r) pmax = fmaxf(pmax, p[1][r]);
    pmax = fmaxf(pmax, __shfl_xor(pmax, 32));

    if (__any((pmax - mrun)*cs > 8.f)){        // defer-max (T13): rescale is rare
      const float mnew = fmaxf(mrun, pmax);
      const float corr = exp2f((mrun - mnew)*cs);
      lrun *= corr;
      mrun = mnew;
      #pragma unroll
      for (int r = 0; r < 16; ++r){
        const int qr = (r & 3) + 8*(r >> 2) + 4*hi;
        const float cf = __shfl(corr, qr);     // corr[q] lives in lane q (and q+32)
        oacc[0][r] *= cf;
        oacc[1][r] *= cf;
      }
    }

    const float nm = -mrun*cs;
    float ps = 0.f;
    #pragma unroll
    for (int t = 0; t < 2; ++t)
      #pragma unroll
      for (int r = 0; r < 16; ++r){
        const float e = exp2f(fmaf(p[t][r], cs, nm));
        p[t][r] = e;
        ps += e;
      }
    ps += __shfl_xor(ps, 32);
    lrun += ps;

    // ---- P -> bf16 A-frags fully in-register (16 cvt_pk + 8 permlane32_swap)
    // p[t][reg] holds key kl=(reg&3)+8*(reg>>2)+4hi (within 32-key tile t), q=l31.
    uint32_t pk[2][2][4];
    #pragma unroll
    for (int t = 0; t < 2; ++t)
      #pragma unroll
      for (int c = 0; c < 2; ++c)
        #pragma unroll
        for (int w = 0; w < 4; ++w){
          uint32_t rr;
          asm("v_cvt_pk_bf16_f32 %0, %1, %2"
              : "=v"(rr) : "v"(p[t][8*c + 2*w]), "v"(p[t][8*c + 2*w + 1]));
          pk[t][c][w] = rr;
        }

    #pragma unroll
    for (int ks = 0; ks < 4; ++ks){
      const int t = ks >> 1, c = ks & 1;
      uint32_t w0 = pk[t][c][0], w2 = pk[t][c][2];
      uint32_t w1 = pk[t][c][1], w3 = pk[t][c][3];
      plane32_swap(w0, w2);   // w0 = frag word0 (j0,1), w2 = word2 (j4,5)
      plane32_swap(w1, w3);   // w1 = word1 (j2,3),      w3 = word3 (j6,7)
      u32x4 fwv; fwv[0] = w0; fwv[1] = w1; fwv[2] = w2; fwv[3] = w3;
      const bf16x8 pa = __builtin_bit_cast(bf16x8, fwv);
      #pragma unroll
      for (int dt = 0; dt < 2; ++dt){
        const int d = dt*32 + l31;
        const bf16x8 vf = *reinterpret_cast<const bf16x8*>(
            &Vs[cur][d*64 + (((2*ks + hi) ^ (d & 7)) * 8)]);
        oacc[dt] = __builtin_amdgcn_mfma_f32_32x32x16_bf16(pa, vf, oacc[dt], 0, 0, 0);
      }
    }
    __syncthreads();   // drains gload_lds (next tile ready) + all waves done with cur
  }

  // ---- epilogue: normalize, write [b][s][h*64+d]
  const float linv = 1.f / lrun;
  const int b = bh >> 4, h = bh & 15;
  #pragma unroll
  for (int r = 0; r < 16; ++r){
    const int qr = (r & 3) + 8*(r >> 2) + 4*hi;
    const float li = __shfl(linv, qr);
    const int s = q0 + qr;
    #pragma unroll
    for (int dt = 0; dt < 2; ++dt){
      const int d = dt*32 + l31;
      Ob[((size_t)b*SEQ + s)*DMODEL + h*64 + d] = f2bf(oacc[dt][r] * li);
    }
  }
}

extern "C" void kernel_launch(void* const* d_in, const int* in_sizes, int n_in,
                              void* d_out, int out_size, void* d_ws, size_t ws_size,
                              hipStream_t stream)
{
  const float* x    = (const float*)d_in[0];
  const float* Wqkv = (const float*)d_in[1];
  const float* bqkv = (const float*)d_in[2];
  const float* Wout = (const float*)d_in[3];
  const float* bout = (const float*)d_in[4];
  float* out = (float*)d_out;

  short* ws  = (short*)d_ws;
  short* xb  = ws;                                  // [8192][1024] bf16; reused as attn output
  short* wqt = xb  + (size_t)MROWS*DMODEL;          // [3072][1024]
  short* wot = wqt + (size_t)N_QKV*DMODEL;          // [1024][1024]
  short* Qb  = wot + (size_t)DMODEL*DMODEL;         // [64][2048][64]
  short* Kb  = Qb  + (size_t)MROWS*DMODEL;
  short* Vt  = Kb  + (size_t)MROWS*DMODEL;          // [64][64][2048]

  k_cvt<<<dim3(MROWS*DMODEL/4/256), dim3(256), 0, stream>>>(x, xb, MROWS*DMODEL/4);
  k_cvt_t<<<dim3(N_QKV/64, DMODEL/64), dim3(256), 0, stream>>>(Wqkv, wqt, DMODEL, N_QKV);
  k_cvt_t<<<dim3(DMODEL/64, DMODEL/64), dim3(256), 0, stream>>>(Wout, wot, DMODEL, DMODEL);

  k_gemm<0><<<dim3(N_QKV/128, MROWS/128), dim3(256), 0, stream>>>(
      xb, wqt, bqkv, Qb, Kb, Vt, nullptr, DMODEL);

  k_attn<<<dim3(SEQ/128, BATCH*NUM_HEADS), dim3(256), 0, stream>>>(Qb, Kb, Vt, xb);

  k_gemm<1><<<dim3(DMODEL/128, MROWS/128), dim3(256), 0, stream>>>(
      xb, wot, bout, nullptr, nullptr, nullptr, out, DMODEL);
}

// Round 4
// 300.801 us; speedup vs baseline: 1.3996x; 1.1267x over previous
//
#include <hip/hip_runtime.h>
#include <cstdint>
#include <cstddef>

#define NUM_HEADS 16
#define HEAD_DIM  64
#define DMODEL    1024
#define BATCH     4
#define SEQ       2048
#define MROWS     (BATCH*SEQ)   // 8192
#define N_QKV     (3*DMODEL)    // 3072

// softmax scale folded into Q at GEMM1 epilogue: 1/sqrt(64) * log2(e)
#define QSCALE 0.18033688011111793f

typedef __attribute__((ext_vector_type(8))) short bf16x8;
typedef __attribute__((ext_vector_type(4))) float f32x4;
typedef __attribute__((ext_vector_type(16))) float f32x16;
typedef __attribute__((ext_vector_type(4))) uint32_t u32x4;

__device__ __forceinline__ short f2bf(float f){
  union { float f; uint32_t u; } w; w.f = f;
  uint32_t r = w.u + 0x7fffu + ((w.u >> 16) & 1u);
  return (short)(r >> 16);
}

typedef __attribute__((address_space(3))) short       lds_short_t;
typedef __attribute__((address_space(1))) const short glb_short_t;

// dest = wave-uniform LDS base; HW writes base + lane*16 (16B per lane)
__device__ __forceinline__ void gload_lds16(const short* g, short* lds){
  __builtin_amdgcn_global_load_lds((glb_short_t*)g, (lds_short_t*)lds, 16, 0, 0);
}

// exchange: a' = {a.lo, b.lo(partner)}, b' = {a.hi(partner), b.hi}
__device__ __forceinline__ void plane32_swap(uint32_t &a, uint32_t &b){
#if __has_builtin(__builtin_amdgcn_permlane32_swap)
  auto r = __builtin_amdgcn_permlane32_swap(a, b, false, false);
  a = r[0]; b = r[1];
#else
  asm volatile("v_permlane32_swap_b32 %0, %1" : "+v"(a), "+v"(b));
#endif
}

// raw v_exp_f32 (args <= 8 here; deep-negative underflow->0 is desired)
__device__ __forceinline__ float exp2r(float x){
#if __has_builtin(__builtin_amdgcn_exp2f)
  return __builtin_amdgcn_exp2f(x);
#else
  return exp2f(x);
#endif
}

__device__ __forceinline__ float max3f(float a, float b, float c){
  float d; asm("v_max3_f32 %0, %1, %2, %3" : "=v"(d) : "v"(a), "v"(b), "v"(c));
  return d;
}

// max of 16 floats: 5 max3 over 15 elems, then max3 of partials + last
__device__ __forceinline__ float max16(const f32x16& p){
  float a0 = max3f(p[0],  p[1],  p[2]);
  float a1 = max3f(p[3],  p[4],  p[5]);
  float a2 = max3f(p[6],  p[7],  p[8]);
  float a3 = max3f(p[9],  p[10], p[11]);
  float a4 = max3f(p[12], p[13], p[14]);
  return fmaxf(max3f(a0, a1, a2), max3f(a3, a4, p[15]));
}

// ---------------- f32 -> bf16, same layout (4 elems/thread) ----------------
__global__ void k_cvt(const float* __restrict__ in, short* __restrict__ out, int n4){
  int i = blockIdx.x*256 + threadIdx.x;
  if (i >= n4) return;
  float4 v = reinterpret_cast<const float4*>(in)[i];
  short4 o; o.x = f2bf(v.x); o.y = f2bf(v.y); o.z = f2bf(v.z); o.w = f2bf(v.w);
  reinterpret_cast<short4*>(out)[i] = o;
}

// ---------------- f32 [R][C] -> bf16 [C][R] (64x64 LDS tile) ----------------
__global__ void k_cvt_t(const float* __restrict__ in, short* __restrict__ out, int R, int C){
  __shared__ short t[64][65];
  int cb = blockIdx.x*64, rb = blockIdx.y*64;
  int tx = threadIdx.x & 63, ty = threadIdx.x >> 6;
  #pragma unroll
  for (int i = ty; i < 64; i += 4)
    t[i][tx] = f2bf(in[(size_t)(rb+i)*C + cb + tx]);
  __syncthreads();
  #pragma unroll
  for (int i = ty; i < 64; i += 4)
    out[(size_t)(cb+i)*R + rb + tx] = t[tx][i];
}

// ---------------- 128x128 bf16 GEMM, BK=32, 4 waves ----------------
template<int MODE>
__global__ __launch_bounds__(256, 2) void k_gemm(
    const short* __restrict__ A, const short* __restrict__ Bt,
    const float* __restrict__ bias,
    short* __restrict__ Qb, short* __restrict__ Kb, short* __restrict__ Vt,
    float* __restrict__ Out, int K)
{
  __shared__ short As[128*32];
  __shared__ short Bs[128*32];
  const int lane = threadIdx.x & 63, wave = threadIdx.x >> 6;
  const int wr = wave >> 1, wc = wave & 1;
  const int m0 = blockIdx.y * 128, n0 = blockIdx.x * 128;

  f32x4 acc[4][4] = {};

  const int srow = lane >> 2;
  const int sseg = (lane & 3) ^ (srow & 3);
  const int nkt = K >> 5;
  for (int kt = 0; kt < nkt; ++kt){
    __syncthreads();
    #pragma unroll
    for (int c = 0; c < 2; ++c){
      const int ch = wave*2 + c;
      const int r  = ch*16 + srow;
      gload_lds16(A  + (size_t)(m0 + r)*K + kt*32 + sseg*8, As + ch*512);
      gload_lds16(Bt + (size_t)(n0 + r)*K + kt*32 + sseg*8, Bs + ch*512);
    }
    __syncthreads();
    bf16x8 af[4], bfr[4];
    #pragma unroll
    for (int m = 0; m < 4; ++m){
      const int ra = wr*64 + m*16 + (lane & 15);
      af[m]  = *reinterpret_cast<const bf16x8*>(As + ra*32 + (((lane>>4) ^ (ra & 3))*8));
      const int rb = wc*64 + m*16 + (lane & 15);
      bfr[m] = *reinterpret_cast<const bf16x8*>(Bs + rb*32 + (((lane>>4) ^ (rb & 3))*8));
    }
    #pragma unroll
    for (int m = 0; m < 4; ++m)
      #pragma unroll
      for (int n = 0; n < 4; ++n)
        acc[m][n] = __builtin_amdgcn_mfma_f32_16x16x32_bf16(af[m], bfr[n], acc[m][n], 0, 0, 0);
  }

  #pragma unroll
  for (int m = 0; m < 4; ++m){
    const int row = m0 + wr*64 + m*16 + ((lane>>4)<<2);
    #pragma unroll
    for (int n = 0; n < 4; ++n){
      const int col = n0 + wc*64 + n*16 + (lane & 15);
      const float bv = bias[col];
      #pragma unroll
      for (int i = 0; i < 4; ++i){
        const int r = row + i;
        const float v = acc[m][n][i] + bv;
        if (MODE == 0){
          const int h = col / 192, q = col % 192;
          const int b = r >> 11, s = r & 2047;
          const int bh = b*NUM_HEADS + h;
          if (q < 64)       Qb[((size_t)bh*SEQ + s)*64 + q]          = f2bf(v * QSCALE);
          else if (q < 128) Kb[((size_t)bh*SEQ + s)*64 + (q-64)]     = f2bf(v);
          else              Vt[((size_t)bh*64 + (q-128))*SEQ + s]    = f2bf(v);
        } else {
          Out[(size_t)r*DMODEL + col] = v;
        }
      }
    }
  }
}

// ---------------- flash attention (R2 structure): swapped QK^T, in-register softmax ----
// 4 waves x 32 q-rows = 128 q/block. KVBLK=64, K/V double-buffered in LDS.
// Qb (pre-scaled by QSCALE), Kb [bh][S][64] bf16 ; Vt [bh][64][S] bf16
// Ob [b][s][h*64+d] bf16
__global__ __launch_bounds__(256, 3) void k_attn(
    const short* __restrict__ Qb, const short* __restrict__ Kb,
    const short* __restrict__ Vt, short* __restrict__ Ob)
{
  __shared__ short Ks[2][64*64];   // [key][d], 16B-seg swizzle ^ (key&7)
  __shared__ short Vs[2][64*64];   // [d][key], 16B-seg swizzle ^ (d&7)
  const int lane = threadIdx.x & 63, wave = threadIdx.x >> 6;
  const int l31 = lane & 31, hi = lane >> 5;
  const int bh = blockIdx.y;
  const int q0 = blockIdx.x*128 + wave*32;

  // Q fragments: lane owns q-row q0+l31; qf[ks] covers d = 16ks + 8hi .. +8
  bf16x8 qf[4];
  {
    const short* qrow = Qb + ((size_t)bh*SEQ + q0 + l31)*64;
    #pragma unroll
    for (int ks = 0; ks < 4; ++ks)
      qf[ks] = *reinterpret_cast<const bf16x8*>(qrow + ks*16 + hi*8);
  }

  f32x16 oacc[2] = {};          // O in C-layout: row q=(r&3)+8*(r>>2)+4hi, col d=dt*32+l31
  float mrun = -1e30f, lrun = 0.f;

  const int r8 = lane >> 3, sg = lane & 7;

  auto stage = [&](int bsel, int kt){
    #pragma unroll
    for (int c = 0; c < 2; ++c){
      const int ch  = wave*2 + c;
      const int row = ch*8 + r8;
      const int seg = sg ^ (row & 7);
      gload_lds16(Kb + ((size_t)bh*SEQ + kt*64 + row)*64 + seg*8, &Ks[bsel][ch*512]);
      gload_lds16(Vt + ((size_t)bh*64 + row)*SEQ + kt*64 + seg*8, &Vs[bsel][ch*512]);
    }
  };

  stage(0, 0);
  __syncthreads();

  for (int kt = 0; kt < SEQ/64; ++kt){
    const int cur = kt & 1;
    if (kt < SEQ/64 - 1) stage(cur ^ 1, kt + 1);

    // ---- swapped QK^T: p[t] = K_tile(t) x Q^T ; lane holds 16 keys of its q-row
    f32x16 p[2] = {};
    #pragma unroll
    for (int t = 0; t < 2; ++t){
      const int key = t*32 + l31;
      const short* krow = &Ks[cur][key*64];
      const int sw = key & 7;
      #pragma unroll
      for (int ks = 0; ks < 4; ++ks){
        const bf16x8 kf = *reinterpret_cast<const bf16x8*>(krow + (((2*ks + hi) ^ sw) * 8));
        p[t] = __builtin_amdgcn_mfma_f32_32x32x16_bf16(kf, qf[ks], p[t], 0, 0, 0);
      }
    }

    // ---- online softmax: row max/sum in-lane + 1 partner swap (scores in exp2 domain)
    float pmax = fmaxf(max16(p[0]), max16(p[1]));
    pmax = fmaxf(pmax, __shfl_xor(pmax, 32));

    if (__any(pmax - mrun > 8.f)){           // defer-max (T13): rescale is rare
      const float mnew = fmaxf(mrun, pmax);
      const float corr = exp2r(mrun - mnew);
      lrun *= corr;
      mrun = mnew;
      #pragma unroll
      for (int r = 0; r < 16; ++r){
        const int qr = (r & 3) + 8*(r >> 2) + 4*hi;
        const float cf = __shfl(corr, qr);   // corr[q] lives in lane q (and q+32)
        oacc[0][r] *= cf;
        oacc[1][r] *= cf;
      }
    }

    float ps = 0.f;
    #pragma unroll
    for (int t = 0; t < 2; ++t)
      #pragma unroll
      for (int r = 0; r < 16; ++r){
        const float e = exp2r(p[t][r] - mrun);
        p[t][r] = e;
        ps += e;
      }
    ps += __shfl_xor(ps, 32);
    lrun += ps;

    // ---- P -> bf16 A-frags fully in-register (16 cvt_pk + 8 permlane32_swap)
    // p[t][reg] holds key kl=(reg&3)+8*(reg>>2)+4hi (within 32-key tile t), q=l31.
    uint32_t pk[2][2][4];
    #pragma unroll
    for (int t = 0; t < 2; ++t)
      #pragma unroll
      for (int c = 0; c < 2; ++c)
        #pragma unroll
        for (int w = 0; w < 4; ++w){
          uint32_t rr;
          asm("v_cvt_pk_bf16_f32 %0, %1, %2"
              : "=v"(rr) : "v"(p[t][8*c + 2*w]), "v"(p[t][8*c + 2*w + 1]));
          pk[t][c][w] = rr;
        }

    #pragma unroll
    for (int ks = 0; ks < 4; ++ks){
      const int t = ks >> 1, c = ks & 1;
      uint32_t w0 = pk[t][c][0], w2 = pk[t][c][2];
      uint32_t w1 = pk[t][c][1], w3 = pk[t][c][3];
      plane32_swap(w0, w2);   // w0 = frag word0 (j0,1), w2 = word2 (j4,5)
      plane32_swap(w1, w3);   // w1 = word1 (j2,3),      w3 = word3 (j6,7)
      u32x4 fwv; fwv[0] = w0; fwv[1] = w1; fwv[2] = w2; fwv[3] = w3;
      const bf16x8 pa = __builtin_bit_cast(bf16x8, fwv);
      #pragma unroll
      for (int dt = 0; dt < 2; ++dt){
        const int d = dt*32 + l31;
        const bf16x8 vf = *reinterpret_cast<const bf16x8*>(
            &Vs[cur][d*64 + (((2*ks + hi) ^ (d & 7)) * 8)]);
        oacc[dt] = __builtin_amdgcn_mfma_f32_32x32x16_bf16(pa, vf, oacc[dt], 0, 0, 0);
      }
    }
    __syncthreads();   // drains gload_lds (next tile ready) + all waves done with cur
  }

  // ---- epilogue: normalize, write [b][s][h*64+d]
  const float linv = 1.f / lrun;
  const int b = bh >> 4, h = bh & 15;
  #pragma unroll
  for (int r = 0; r < 16; ++r){
    const int qr = (r & 3) + 8*(r >> 2) + 4*hi;
    const float li = __shfl(linv, qr);
    const int s = q0 + qr;
    #pragma unroll
    for (int dt = 0; dt < 2; ++dt){
      const int d = dt*32 + l31;
      Ob[((size_t)b*SEQ + s)*DMODEL + h*64 + d] = f2bf(oacc[dt][r] * li);
    }
  }
}

extern "C" void kernel_launch(void* const* d_in, const int* in_sizes, int n_in,
                              void* d_out, int out_size, void* d_ws, size_t ws_size,
                              hipStream_t stream)
{
  const float* x    = (const float*)d_in[0];
  const float* Wqkv = (const float*)d_in[1];
  const float* bqkv = (const float*)d_in[2];
  const float* Wout = (const float*)d_in[3];
  const float* bout = (const float*)d_in[4];
  float* out = (float*)d_out;

  short* ws  = (short*)d_ws;
  short* xb  = ws;                                  // [8192][1024] bf16; reused as attn output
  short* wqt = xb  + (size_t)MROWS*DMODEL;          // [3072][1024]
  short* wot = wqt + (size_t)N_QKV*DMODEL;          // [1024][1024]
  short* Qb  = wot + (size_t)DMODEL*DMODEL;         // [64][2048][64]
  short* Kb  = Qb  + (size_t)MROWS*DMODEL;
  short* Vt  = Kb  + (size_t)MROWS*DMODEL;          // [64][64][2048]

  k_cvt<<<dim3(MROWS*DMODEL/4/256), dim3(256), 0, stream>>>(x, xb, MROWS*DMODEL/4);
  k_cvt_t<<<dim3(N_QKV/64, DMODEL/64), dim3(256), 0, stream>>>(Wqkv, wqt, DMODEL, N_QKV);
  k_cvt_t<<<dim3(DMODEL/64, DMODEL/64), dim3(256), 0, stream>>>(Wout, wot, DMODEL, DMODEL);

  k_gemm<0><<<dim3(N_QKV/128, MROWS/128), dim3(256), 0, stream>>>(
      xb, wqt, bqkv, Qb, Kb, Vt, nullptr, DMODEL);

  k_attn<<<dim3(SEQ/128, BATCH*NUM_HEADS), dim3(256), 0, stream>>>(Qb, Kb, Vt, xb);

  k_gemm<1><<<dim3(DMODEL/128, MROWS/128), dim3(256), 0, stream>>>(
      xb, wot, bout, nullptr, nullptr, nullptr, out, DMODEL);
}

// Round 5
// 293.595 us; speedup vs baseline: 1.4339x; 1.0245x over previous
//
#include <hip/hip_runtime.h>
#include <cstdint>
#include <cstddef>

#define NUM_HEADS 16
#define HEAD_DIM  64
#define DMODEL    1024
#define BATCH     4
#define SEQ       2048
#define MROWS     (BATCH*SEQ)   // 8192
#define N_QKV     (3*DMODEL)    // 3072

// softmax scale folded into Q at GEMM1 epilogue: 1/sqrt(64) * log2(e)
#define QSCALE 0.18033688011111793f

typedef __attribute__((ext_vector_type(8))) short bf16x8;
typedef __attribute__((ext_vector_type(4))) float f32x4;
typedef __attribute__((ext_vector_type(16))) float f32x16;
typedef __attribute__((ext_vector_type(4))) uint32_t u32x4;

__device__ __forceinline__ short f2bf(float f){
  union { float f; uint32_t u; } w; w.f = f;
  uint32_t r = w.u + 0x7fffu + ((w.u >> 16) & 1u);
  return (short)(r >> 16);
}

typedef __attribute__((address_space(3))) short       lds_short_t;
typedef __attribute__((address_space(1))) const short glb_short_t;

// dest = wave-uniform LDS base; HW writes base + lane*16 (16B per lane)
__device__ __forceinline__ void gload_lds16(const short* g, short* lds){
  __builtin_amdgcn_global_load_lds((glb_short_t*)g, (lds_short_t*)lds, 16, 0, 0);
}

// exchange: a' = {a.lo, b.lo(partner)}, b' = {a.hi(partner), b.hi}
__device__ __forceinline__ void plane32_swap(uint32_t &a, uint32_t &b){
#if __has_builtin(__builtin_amdgcn_permlane32_swap)
  auto r = __builtin_amdgcn_permlane32_swap(a, b, false, false);
  a = r[0]; b = r[1];
#else
  asm volatile("v_permlane32_swap_b32 %0, %1" : "+v"(a), "+v"(b));
#endif
}

// raw v_exp_f32 (args <= 8 here; deep-negative underflow->0 is desired)
__device__ __forceinline__ float exp2r(float x){
#if __has_builtin(__builtin_amdgcn_exp2f)
  return __builtin_amdgcn_exp2f(x);
#else
  return exp2f(x);
#endif
}

__device__ __forceinline__ float max3f(float a, float b, float c){
  float d; asm("v_max3_f32 %0, %1, %2, %3" : "=v"(d) : "v"(a), "v"(b), "v"(c));
  return d;
}

// max of 16 floats: 5 max3 over 15 elems, then max3 of partials + last
__device__ __forceinline__ float max16(const f32x16& p){
  float a0 = max3f(p[0],  p[1],  p[2]);
  float a1 = max3f(p[3],  p[4],  p[5]);
  float a2 = max3f(p[6],  p[7],  p[8]);
  float a3 = max3f(p[9],  p[10], p[11]);
  float a4 = max3f(p[12], p[13], p[14]);
  return fmaxf(max3f(a0, a1, a2), max3f(a3, a4, p[15]));
}

// ---------------- f32 -> bf16, same layout (4 elems/thread) ----------------
__global__ void k_cvt(const float* __restrict__ in, short* __restrict__ out, int n4){
  int i = blockIdx.x*256 + threadIdx.x;
  if (i >= n4) return;
  float4 v = reinterpret_cast<const float4*>(in)[i];
  short4 o; o.x = f2bf(v.x); o.y = f2bf(v.y); o.z = f2bf(v.z); o.w = f2bf(v.w);
  reinterpret_cast<short4*>(out)[i] = o;
}

// ---------------- f32 [R][C] -> bf16 [C][R] (64x64 LDS tile) ----------------
__global__ void k_cvt_t(const float* __restrict__ in, short* __restrict__ out, int R, int C){
  __shared__ short t[64][65];
  int cb = blockIdx.x*64, rb = blockIdx.y*64;
  int tx = threadIdx.x & 63, ty = threadIdx.x >> 6;
  #pragma unroll
  for (int i = ty; i < 64; i += 4)
    t[i][tx] = f2bf(in[(size_t)(rb+i)*C + cb + tx]);
  __syncthreads();
  #pragma unroll
  for (int i = ty; i < 64; i += 4)
    out[(size_t)(cb+i)*R + rb + tx] = t[tx][i];
}

// ---------------- 128x128 bf16 GEMM, BK=32, 4 waves, double-buffered LDS ----
// T3-minimum 2-phase: stage(next) issued BEFORE compute(cur); one barrier/iter
// (its implicit vmcnt(0)+lgkmcnt(0) drain sits after ~300cy of MFMA work).
template<int MODE>
__global__ __launch_bounds__(256, 3) void k_gemm(
    const short* __restrict__ A, const short* __restrict__ Bt,
    const float* __restrict__ bias,
    short* __restrict__ Qb, short* __restrict__ Kb, short* __restrict__ Vt,
    float* __restrict__ Out, int K)
{
  __shared__ short As[2][128*32];
  __shared__ short Bs[2][128*32];
  const int lane = threadIdx.x & 63, wave = threadIdx.x >> 6;
  const int wr = wave >> 1, wc = wave & 1;
  const int m0 = blockIdx.y * 128, n0 = blockIdx.x * 128;

  f32x4 acc[4][4] = {};

  const int srow = lane >> 2;
  const int sseg = (lane & 3) ^ (srow & 3);
  const int nkt = K >> 5;

  auto stage = [&](int bsel, int kt){
    #pragma unroll
    for (int c = 0; c < 2; ++c){
      const int ch = wave*2 + c;
      const int r  = ch*16 + srow;
      gload_lds16(A  + (size_t)(m0 + r)*K + kt*32 + sseg*8, &As[bsel][ch*512]);
      gload_lds16(Bt + (size_t)(n0 + r)*K + kt*32 + sseg*8, &Bs[bsel][ch*512]);
    }
  };

  stage(0, 0);
  __syncthreads();

  for (int kt = 0; kt < nkt; ++kt){
    const int cur = kt & 1;
    if (kt + 1 < nkt) stage(cur ^ 1, kt + 1);   // overlap next-tile HBM/L2 latency

    bf16x8 af[4], bfr[4];
    #pragma unroll
    for (int m = 0; m < 4; ++m){
      const int ra = wr*64 + m*16 + (lane & 15);
      af[m]  = *reinterpret_cast<const bf16x8*>(&As[cur][ra*32 + (((lane>>4) ^ (ra & 3))*8)]);
      const int rb = wc*64 + m*16 + (lane & 15);
      bfr[m] = *reinterpret_cast<const bf16x8*>(&Bs[cur][rb*32 + (((lane>>4) ^ (rb & 3))*8)]);
    }
    #pragma unroll
    for (int m = 0; m < 4; ++m)
      #pragma unroll
      for (int n = 0; n < 4; ++n)
        acc[m][n] = __builtin_amdgcn_mfma_f32_16x16x32_bf16(af[m], bfr[n], acc[m][n], 0, 0, 0);

    __syncthreads();   // drains this wave's stage loads; all waves done reading cur
  }

  #pragma unroll
  for (int m = 0; m < 4; ++m){
    const int row = m0 + wr*64 + m*16 + ((lane>>4)<<2);
    #pragma unroll
    for (int n = 0; n < 4; ++n){
      const int col = n0 + wc*64 + n*16 + (lane & 15);
      const float bv = bias[col];
      #pragma unroll
      for (int i = 0; i < 4; ++i){
        const int r = row + i;
        const float v = acc[m][n][i] + bv;
        if (MODE == 0){
          const int h = col / 192, q = col % 192;
          const int b = r >> 11, s = r & 2047;
          const int bh = b*NUM_HEADS + h;
          if (q < 64)       Qb[((size_t)bh*SEQ + s)*64 + q]          = f2bf(v * QSCALE);
          else if (q < 128) Kb[((size_t)bh*SEQ + s)*64 + (q-64)]     = f2bf(v);
          else              Vt[((size_t)bh*64 + (q-128))*SEQ + s]    = f2bf(v);
        } else {
          Out[(size_t)r*DMODEL + col] = v;
        }
      }
    }
  }
}

// ---------------- flash attention (R2 structure): swapped QK^T, in-register softmax ----
// 4 waves x 32 q-rows = 128 q/block. KVBLK=64, K/V double-buffered in LDS.
// Qb (pre-scaled by QSCALE), Kb [bh][S][64] bf16 ; Vt [bh][64][S] bf16
// Ob [b][s][h*64+d] bf16
__global__ __launch_bounds__(256, 3) void k_attn(
    const short* __restrict__ Qb, const short* __restrict__ Kb,
    const short* __restrict__ Vt, short* __restrict__ Ob)
{
  __shared__ short Ks[2][64*64];   // [key][d], 16B-seg swizzle ^ (key&7)
  __shared__ short Vs[2][64*64];   // [d][key], 16B-seg swizzle ^ (d&7)
  const int lane = threadIdx.x & 63, wave = threadIdx.x >> 6;
  const int l31 = lane & 31, hi = lane >> 5;
  const int bh = blockIdx.y;
  const int q0 = blockIdx.x*128 + wave*32;

  // Q fragments: lane owns q-row q0+l31; qf[ks] covers d = 16ks + 8hi .. +8
  bf16x8 qf[4];
  {
    const short* qrow = Qb + ((size_t)bh*SEQ + q0 + l31)*64;
    #pragma unroll
    for (int ks = 0; ks < 4; ++ks)
      qf[ks] = *reinterpret_cast<const bf16x8*>(qrow + ks*16 + hi*8);
  }

  f32x16 oacc[2] = {};          // O in C-layout: row q=(r&3)+8*(r>>2)+4hi, col d=dt*32+l31
  float mrun = -1e30f, lrun = 0.f;

  const int r8 = lane >> 3, sg = lane & 7;

  auto stage = [&](int bsel, int kt){
    #pragma unroll
    for (int c = 0; c < 2; ++c){
      const int ch  = wave*2 + c;
      const int row = ch*8 + r8;
      const int seg = sg ^ (row & 7);
      gload_lds16(Kb + ((size_t)bh*SEQ + kt*64 + row)*64 + seg*8, &Ks[bsel][ch*512]);
      gload_lds16(Vt + ((size_t)bh*64 + row)*SEQ + kt*64 + seg*8, &Vs[bsel][ch*512]);
    }
  };

  stage(0, 0);
  __syncthreads();

  for (int kt = 0; kt < SEQ/64; ++kt){
    const int cur = kt & 1;
    if (kt < SEQ/64 - 1) stage(cur ^ 1, kt + 1);

    // ---- swapped QK^T: p[t] = K_tile(t) x Q^T ; lane holds 16 keys of its q-row
    f32x16 p[2] = {};
    #pragma unroll
    for (int t = 0; t < 2; ++t){
      const int key = t*32 + l31;
      const short* krow = &Ks[cur][key*64];
      const int sw = key & 7;
      #pragma unroll
      for (int ks = 0; ks < 4; ++ks){
        const bf16x8 kf = *reinterpret_cast<const bf16x8*>(krow + (((2*ks + hi) ^ sw) * 8));
        p[t] = __builtin_amdgcn_mfma_f32_32x32x16_bf16(kf, qf[ks], p[t], 0, 0, 0);
      }
    }

    // ---- online softmax: row max/sum in-lane + 1 partner swap (scores in exp2 domain)
    float pmax = fmaxf(max16(p[0]), max16(p[1]));
    pmax = fmaxf(pmax, __shfl_xor(pmax, 32));

    if (__any(pmax - mrun > 8.f)){           // defer-max (T13): rescale is rare
      const float mnew = fmaxf(mrun, pmax);
      const float corr = exp2r(mrun - mnew);
      lrun *= corr;
      mrun = mnew;
      #pragma unroll
      for (int r = 0; r < 16; ++r){
        const int qr = (r & 3) + 8*(r >> 2) + 4*hi;
        const float cf = __shfl(corr, qr);   // corr[q] lives in lane q (and q+32)
        oacc[0][r] *= cf;
        oacc[1][r] *= cf;
      }
    }

    float ps = 0.f;
    #pragma unroll
    for (int t = 0; t < 2; ++t)
      #pragma unroll
      for (int r = 0; r < 16; ++r){
        const float e = exp2r(p[t][r] - mrun);
        p[t][r] = e;
        ps += e;
      }
    ps += __shfl_xor(ps, 32);
    lrun += ps;

    // ---- P -> bf16 A-frags fully in-register (16 cvt_pk + 8 permlane32_swap)
    // p[t][reg] holds key kl=(reg&3)+8*(reg>>2)+4hi (within 32-key tile t), q=l31.
    uint32_t pk[2][2][4];
    #pragma unroll
    for (int t = 0; t < 2; ++t)
      #pragma unroll
      for (int c = 0; c < 2; ++c)
        #pragma unroll
        for (int w = 0; w < 4; ++w){
          uint32_t rr;
          asm("v_cvt_pk_bf16_f32 %0, %1, %2"
              : "=v"(rr) : "v"(p[t][8*c + 2*w]), "v"(p[t][8*c + 2*w + 1]));
          pk[t][c][w] = rr;
        }

    #pragma unroll
    for (int ks = 0; ks < 4; ++ks){
      const int t = ks >> 1, c = ks & 1;
      uint32_t w0 = pk[t][c][0], w2 = pk[t][c][2];
      uint32_t w1 = pk[t][c][1], w3 = pk[t][c][3];
      plane32_swap(w0, w2);   // w0 = frag word0 (j0,1), w2 = word2 (j4,5)
      plane32_swap(w1, w3);   // w1 = word1 (j2,3),      w3 = word3 (j6,7)
      u32x4 fwv; fwv[0] = w0; fwv[1] = w1; fwv[2] = w2; fwv[3] = w3;
      const bf16x8 pa = __builtin_bit_cast(bf16x8, fwv);
      #pragma unroll
      for (int dt = 0; dt < 2; ++dt){
        const int d = dt*32 + l31;
        const bf16x8 vf = *reinterpret_cast<const bf16x8*>(
            &Vs[cur][d*64 + (((2*ks + hi) ^ (d & 7)) * 8)]);
        oacc[dt] = __builtin_amdgcn_mfma_f32_32x32x16_bf16(pa, vf, oacc[dt], 0, 0, 0);
      }
    }
    __syncthreads();   // drains gload_lds (next tile ready) + all waves done with cur
  }

  // ---- epilogue: normalize, write [b][s][h*64+d]
  const float linv = 1.f / lrun;
  const int b = bh >> 4, h = bh & 15;
  #pragma unroll
  for (int r = 0; r < 16; ++r){
    const int qr = (r & 3) + 8*(r >> 2) + 4*hi;
    const float li = __shfl(linv, qr);
    const int s = q0 + qr;
    #pragma unroll
    for (int dt = 0; dt < 2; ++dt){
      const int d = dt*32 + l31;
      Ob[((size_t)b*SEQ + s)*DMODEL + h*64 + d] = f2bf(oacc[dt][r] * li);
    }
  }
}

extern "C" void kernel_launch(void* const* d_in, const int* in_sizes, int n_in,
                              void* d_out, int out_size, void* d_ws, size_t ws_size,
                              hipStream_t stream)
{
  const float* x    = (const float*)d_in[0];
  const float* Wqkv = (const float*)d_in[1];
  const float* bqkv = (const float*)d_in[2];
  const float* Wout = (const float*)d_in[3];
  const float* bout = (const float*)d_in[4];
  float* out = (float*)d_out;

  short* ws  = (short*)d_ws;
  short* xb  = ws;                                  // [8192][1024] bf16; reused as attn output
  short* wqt = xb  + (size_t)MROWS*DMODEL;          // [3072][1024]
  short* wot = wqt + (size_t)N_QKV*DMODEL;          // [1024][1024]
  short* Qb  = wot + (size_t)DMODEL*DMODEL;         // [64][2048][64]
  short* Kb  = Qb  + (size_t)MROWS*DMODEL;
  short* Vt  = Kb  + (size_t)MROWS*DMODEL;          // [64][64][2048]

  k_cvt<<<dim3(MROWS*DMODEL/4/256), dim3(256), 0, stream>>>(x, xb, MROWS*DMODEL/4);
  k_cvt_t<<<dim3(N_QKV/64, DMODEL/64), dim3(256), 0, stream>>>(Wqkv, wqt, DMODEL, N_QKV);
  k_cvt_t<<<dim3(DMODEL/64, DMODEL/64), dim3(256), 0, stream>>>(Wout, wot, DMODEL, DMODEL);

  k_gemm<0><<<dim3(N_QKV/128, MROWS/128), dim3(256), 0, stream>>>(
      xb, wqt, bqkv, Qb, Kb, Vt, nullptr, DMODEL);

  k_attn<<<dim3(SEQ/128, BATCH*NUM_HEADS), dim3(256), 0, stream>>>(Qb, Kb, Vt, xb);

  k_gemm<1><<<dim3(DMODEL/128, MROWS/128), dim3(256), 0, stream>>>(
      xb, wot, bout, nullptr, nullptr, nullptr, out, DMODEL);
}